// Round 3
// baseline (4280.365 us; speedup 1.0000x reference)
//
#include <hip/hip_runtime.h>

// ---------------------------------------------------------------------------
// Encoder: x=emb[enc]; xp = x@Wx + b_in; reset-after GRU over T=256 steps;
// out = h_last[:, 200:700].  All float inputs fp32; output fp32.
//
// Persistent weight-stationary GRU, per-WAVE dataflow sync (R11):
//   - Consumer wave rt reads ONLY its own 16 rows, produced by same-rt waves
//     of the 22 producer blocks. Producer drains own stores (vmcnt(0) is
//     wave-local), publishes flag[g][slice][wave]; consumer polls 44 flags
//     lane-parallel. NO __syncthreads in the 256-step loop.
//   - 176 blocks; swizzle g=bx&7, s=bx>>3; HW_REG_XCC_ID check selects
//     fast (relaxed flags + l1_inv) or slow (release/acquire) per group.
//   - h fp32 in regs; exchanged as bf16 hi/lo pair through Wh buffer.
//   - d_ws: [8] grid barrier, [16..191] xcc, [256..1279] wave flags.
//   - R12 RESULT: heater blocks on the 80 idle CUs = exact null (2082->2080us,
//     VALUBusy 6->34%). DVFS-via-idle-CUs theory FALSIFIED. Heaters removed.
//   - R13: calibrated probes, GRU core byte-identical. R14 = RESUBMIT of R13
//     (round 2 bench died on container acquisition, no signal on the kernel;
//     probe design has no new deadlock/watchdog path, so infra flake).
//     (a) slack meter: 4096-long DEPENDENT fma chain (~16.4K cyc @ ~4cyc dep
//         latency) per step, inserted in the wait shadow (after x-MFMA +
//         prefetch issue, before the poll). If the ~15K unexplained
//         cycles/step are idle wait at full clock, dur is UNCHANGED and
//         VALUBusy jumps; if the step is throughput-bound at 2.4GHz, dur
//         grows ~+1.75ms; if clock is low, growth is proportionally larger.
//     (b) fast-detector: if !fast, one-time ~21M-cycle burn (+~8.7ms) --
//         unambiguously detects that the bx%8 XCD assumption is wrong and
//         the slow path (per-step threadfence/acquire) is what we measure.
// ---------------------------------------------------------------------------

typedef unsigned short ushort_t;
typedef __bf16 bf16x8 __attribute__((ext_vector_type(8)));
typedef unsigned short ushort8 __attribute__((ext_vector_type(8)));
typedef float floatx4 __attribute__((ext_vector_type(4)));

#define NGRP   8
#define NSLC   22
#define NBLK   176
#define SB     840   // LDS row stride (bf16): 832 + 8 pad
#define HP     704
#define AH_ROW 1408  // hi[704] | lo[704]
#define PHASE  (256 * AH_ROW)
#define FLAGW(gg, ss, ww) (256 + (gg) * 128 + (ss) * 4 + (ww))

__device__ __forceinline__ float bf2f(ushort_t u) {
    unsigned v = ((unsigned)u) << 16; float f; __builtin_memcpy(&f, &v, 4); return f;
}
__device__ __forceinline__ ushort_t f2bf(float f) {
    unsigned u; __builtin_memcpy(&u, &f, 4);
    unsigned r = u + 0x7fff + ((u >> 16) & 1);
    return (ushort_t)(r >> 16);
}
__device__ __forceinline__ bf16x8 ld8(const ushort_t* p) {
    return __builtin_bit_cast(bf16x8, *(const ushort8*)p);
}
__device__ __forceinline__ bf16x8 cvt8(floatx4 a, floatx4 b) {
    ushort8 r = {f2bf(a.x), f2bf(a.y), f2bf(a.z), f2bf(a.w),
                 f2bf(b.x), f2bf(b.y), f2bf(b.z), f2bf(b.w)};
    return __builtin_bit_cast(bf16x8, r);
}
__device__ __forceinline__ void l1_inv() {
    asm volatile("buffer_inv sc0" ::: "memory");
}
__device__ __forceinline__ void wave_drain() {   // wave-local store drain
    asm volatile("s_waitcnt vmcnt(0)" ::: "memory");
}
__device__ __forceinline__ float fast_rcp(float x) {
    float r; asm("v_rcp_f32 %0, %1" : "=v"(r) : "v"(x)); return r;
}
__device__ __forceinline__ float fast_exp(float x) {
    float r; asm("v_exp_f32 %0, %1" : "=v"(r) : "v"(x * 1.44269504f)); return r;
}

__global__ void init_cnt(int* cnt) {
    for (int i = threadIdx.x; i < 1280; i += 1024) cnt[i] = 0;
}

__global__ __launch_bounds__(256, 1) void gru_main(
    const int* __restrict__ enc, const float* __restrict__ emb,
    const float* __restrict__ Wx, float* whf,
    const float* __restrict__ lab, const float* __restrict__ W1,
    const float* __restrict__ b1, const float* __restrict__ bias,
    float* __restrict__ out, int* cnt) {

    extern __shared__ ushort_t Bs[];   // [96][SB] bf16
    const int bx = blockIdx.x;
    const int g = bx & 7, s = bx >> 3;
    const int tid = threadIdx.x;
    const int wave = tid >> 6, lane = tid & 63;
    const int rt = wave >> 1, ct = wave & 1;
    const int q = lane >> 4, m = lane & 15;

    // ---- one-time staging: Bs[p][k] = bf16(W[k][col(p)]), p = gate*32+c ----
    for (int idx = tid; idx < 96 * 832; idx += 256) {
        int p = idx % 96, k = idx / 96;
        int c = s * 32 + (p & 31);
        ushort_t v = 0;
        if (c < 700) {
            int col = (p >> 5) * 700 + c;
            if (k < 100) v = f2bf(Wx[k * 2100 + col]);
            else if (k >= 128 && k < 828) v = f2bf(whf[(k - 128) * 2100 + col]);
        }
        Bs[p * SB + k] = v;
    }
    __syncthreads();   // all Wh reads of this block retired

    // ---- publish xcc id, then grid barrier (agent scope, one-time) ---------
    if (tid == 0) {
        int xcc;
        asm("s_getreg_b32 %0, hwreg(HW_REG_XCC_ID)" : "=s"(xcc));
        __hip_atomic_store(cnt + 16 + bx, xcc, __ATOMIC_RELAXED, __HIP_MEMORY_SCOPE_AGENT);
        __hip_atomic_fetch_add(cnt + 8, 1, __ATOMIC_ACQ_REL, __HIP_MEMORY_SCOPE_AGENT);
        while (__hip_atomic_load(cnt + 8, __ATOMIC_ACQUIRE, __HIP_MEMORY_SCOPE_AGENT) < NBLK)
            __builtin_amdgcn_s_sleep(1);
    }
    __syncthreads();

    // ---- fast iff all 22 peers share an XCD --------------------------------
    bool fast = true;
    {
        int myx = __hip_atomic_load(cnt + 16 + bx, __ATOMIC_RELAXED, __HIP_MEMORY_SCOPE_AGENT);
        for (int s2 = 0; s2 < NSLC; ++s2) {
            int px = __hip_atomic_load(cnt + 16 + g + 8 * s2, __ATOMIC_RELAXED, __HIP_MEMORY_SCOPE_AGENT);
            fast = fast && (px == myx);
        }
    }

    // ---- R13 probe (b): unambiguous fast=false detector (~21M-cycle burn) --
    if (!fast) {
        float pz = (float)(tid + 1);
        for (int u = 0; u < 327680; ++u) {
            pz = __builtin_fmaf(pz, 1.0000001f, 1e-9f);
            pz = __builtin_fmaf(pz, 1.0000001f, 1e-9f);
            pz = __builtin_fmaf(pz, 1.0000001f, 1e-9f);
            pz = __builtin_fmaf(pz, 1.0000001f, 1e-9f);
            pz = __builtin_fmaf(pz, 1.0000001f, 1e-9f);
            pz = __builtin_fmaf(pz, 1.0000001f, 1e-9f);
            pz = __builtin_fmaf(pz, 1.0000001f, 1e-9f);
            pz = __builtin_fmaf(pz, 1.0000001f, 1e-9f);
            pz = __builtin_fmaf(pz, 1.0000001f, 1e-9f);
            pz = __builtin_fmaf(pz, 1.0000001f, 1e-9f);
            pz = __builtin_fmaf(pz, 1.0000001f, 1e-9f);
            pz = __builtin_fmaf(pz, 1.0000001f, 1e-9f);
            pz = __builtin_fmaf(pz, 1.0000001f, 1e-9f);
            pz = __builtin_fmaf(pz, 1.0000001f, 1e-9f);
            pz = __builtin_fmaf(pz, 1.0000001f, 1e-9f);
            pz = __builtin_fmaf(pz, 1.0000001f, 1e-9f);
        }
        asm volatile("" :: "v"(pz));
    }

    const int j = s * 32 + ct * 16 + m;
    float bzc = 0.f, brc = 0.f, b0h = 0.f, b1h = 0.f;
    if (j < 700) {
        bzc = bias[j] + bias[2100 + j];
        brc = bias[700 + j] + bias[2800 + j];
        b0h = bias[1400 + j];
        b1h = bias[3500 + j];
    }
    const int rowa = g * 32 + rt * 16 + m;

    ushort_t* Ah = (ushort_t*)whf;
    int* myflag = cnt + FLAGW(g, s, wave);
    // consumer wave rt needs flags (s2, rt*2+ct') for s2=0..21, ct'=0..1
    int* pollp = (lane < 44)
               ? (cnt + FLAGW(g, lane >> 1, rt * 2 + (lane & 1)))
               : (int*)nullptr;

    // ---- h0; publish hi/lo to phase 0 (per-wave) ---------------------------
    float hown[4];
#pragma unroll
    for (int i = 0; i < 4; i++) {
        int rowc = g * 32 + rt * 16 + q * 4 + i;
        float v = 0.f;
        if (j < 200) v = lab[rowc] * W1[j] + b1[j];
        hown[i] = v;
        ushort_t hi = f2bf(v);
        Ah[rowc * AH_ROW + j] = hi;
        Ah[rowc * AH_ROW + HP + j] = f2bf(v - bf2f(hi));
    }
    if (fast) {
        wave_drain();
        if (lane == 0)
            __hip_atomic_store(myflag, 1, __ATOMIC_RELAXED, __HIP_MEMORY_SCOPE_AGENT);
    } else {
        if (lane == 0)
            __hip_atomic_store(myflag, 1, __ATOMIC_RELEASE, __HIP_MEMORY_SCOPE_AGENT);
        else
            __threadfence();
    }

    const ushort_t* bsz = Bs + (ct * 16 + m) * SB;
    const ushort_t* bsr = Bs + (32 + ct * 16 + m) * SB;
    const ushort_t* bsh = Bs + (64 + ct * 16 + m) * SB;

    // ---- initial x prefetch for t=0 ----------------------------------------
    floatx4 pf[6]; floatx4 pft;
    {
        int tok = enc[rowa * 256 + 0];
        const float* ep = emb + tok * 100;
#pragma unroll
        for (int kt = 0; kt < 3; ++kt) {
            pf[kt * 2]     = *(const floatx4*)(ep + kt * 32 + q * 8);
            pf[kt * 2 + 1] = *(const floatx4*)(ep + kt * 32 + q * 8 + 4);
        }
        pft = *(const floatx4*)(ep + 96);
    }

    for (int t = 0; t < 256; ++t) {
        const ushort_t* Asrc = Ah + (t & 1) * PHASE;
        ushort_t* Adst = Ah + ((t + 1) & 1) * PHASE;
        floatx4 accz = {0,0,0,0}, accr = {0,0,0,0}, accrh = {0,0,0,0}, accxh = {0,0,0,0};

        // x-part from prefetched registers (off the critical chain)
#pragma unroll
        for (int kt = 0; kt < 3; ++kt) {
            bf16x8 a = cvt8(pf[kt * 2], pf[kt * 2 + 1]);
            int kb = kt * 32 + q * 8;
            accz  = __builtin_amdgcn_mfma_f32_16x16x32_bf16(a, ld8(bsz + kb), accz, 0, 0, 0);
            accr  = __builtin_amdgcn_mfma_f32_16x16x32_bf16(a, ld8(bsr + kb), accr, 0, 0, 0);
            accxh = __builtin_amdgcn_mfma_f32_16x16x32_bf16(a, ld8(bsh + kb), accxh, 0, 0, 0);
        }
        {
            ushort8 t8 = {0, 0, 0, 0, 0, 0, 0, 0};
            if (q == 0) {
                t8[0] = f2bf(pft.x); t8[1] = f2bf(pft.y);
                t8[2] = f2bf(pft.z); t8[3] = f2bf(pft.w);
            }
            bf16x8 a = __builtin_bit_cast(bf16x8, t8);
            int kb = 96 + q * 8;
            accz  = __builtin_amdgcn_mfma_f32_16x16x32_bf16(a, ld8(bsz + kb), accz, 0, 0, 0);
            accr  = __builtin_amdgcn_mfma_f32_16x16x32_bf16(a, ld8(bsr + kb), accr, 0, 0, 0);
            accxh = __builtin_amdgcn_mfma_f32_16x16x32_bf16(a, ld8(bsh + kb), accxh, 0, 0, 0);
        }
        // prefetch x for t+1 (in flight during the wait)
        {
            int tn = (t < 255) ? t + 1 : 255;
            int tok = enc[rowa * 256 + tn];
            const float* ep = emb + tok * 100;
#pragma unroll
            for (int kt = 0; kt < 3; ++kt) {
                pf[kt * 2]     = *(const floatx4*)(ep + kt * 32 + q * 8);
                pf[kt * 2 + 1] = *(const floatx4*)(ep + kt * 32 + q * 8 + 4);
            }
            pft = *(const floatx4*)(ep + 96);
        }

        // ---- R13 probe (a): slack meter — ~16.4K-cycle dependent fma chain
        // in the wait shadow. If the wait is idle latency at full clock, this
        // fits in slack and dur is unchanged (VALUBusy rises instead).
        {
            float dch = accz[0] + (float)t;
            for (int u = 0; u < 256; ++u) {
                dch = __builtin_fmaf(dch, 1.0000001f, 1e-9f);
                dch = __builtin_fmaf(dch, 1.0000001f, 1e-9f);
                dch = __builtin_fmaf(dch, 1.0000001f, 1e-9f);
                dch = __builtin_fmaf(dch, 1.0000001f, 1e-9f);
                dch = __builtin_fmaf(dch, 1.0000001f, 1e-9f);
                dch = __builtin_fmaf(dch, 1.0000001f, 1e-9f);
                dch = __builtin_fmaf(dch, 1.0000001f, 1e-9f);
                dch = __builtin_fmaf(dch, 1.0000001f, 1e-9f);
                dch = __builtin_fmaf(dch, 1.0000001f, 1e-9f);
                dch = __builtin_fmaf(dch, 1.0000001f, 1e-9f);
                dch = __builtin_fmaf(dch, 1.0000001f, 1e-9f);
                dch = __builtin_fmaf(dch, 1.0000001f, 1e-9f);
                dch = __builtin_fmaf(dch, 1.0000001f, 1e-9f);
                dch = __builtin_fmaf(dch, 1.0000001f, 1e-9f);
                dch = __builtin_fmaf(dch, 1.0000001f, 1e-9f);
                dch = __builtin_fmaf(dch, 1.0000001f, 1e-9f);
            }
            asm volatile("" :: "v"(dch));
        }

        // wait (per-wave, lane-parallel over the 44 relevant producer waves)
        if (lane < 44) {
            if (fast) {
                int spin = 0;
                while (__hip_atomic_load(pollp, __ATOMIC_RELAXED, __HIP_MEMORY_SCOPE_AGENT) < t + 1) {
                    if (++spin > 64) __builtin_amdgcn_s_sleep(1);
                }
            } else {
                while (__hip_atomic_load(pollp, __ATOMIC_ACQUIRE, __HIP_MEMORY_SCOPE_AGENT) < t + 1)
                    __builtin_amdgcn_s_sleep(1);
            }
        }
        if (fast) l1_inv();   // fresh L1 for this wave's h reads

        // h-part: 22 K-tiles; ring-buffer prefetch depth 8 of hi/lo A-frags
        const ushort_t* arow = Asrc + rowa * AH_ROW + q * 8;
        bf16x8 ra[8], rb[8];
#pragma unroll
        for (int p = 0; p < 8; ++p) {
            ra[p] = ld8(arow + p * 32);
            rb[p] = ld8(arow + HP + p * 32);
        }
#pragma unroll
        for (int kt = 0; kt < 22; ++kt) {
            bf16x8 ahi = ra[kt & 7];
            bf16x8 alo = rb[kt & 7];
            if (kt + 8 < 22) {
                ra[kt & 7] = ld8(arow + (kt + 8) * 32);
                rb[kt & 7] = ld8(arow + HP + (kt + 8) * 32);
            }
            int kb = 128 + kt * 32 + q * 8;
            bf16x8 bz8 = ld8(bsz + kb), br8 = ld8(bsr + kb), bh8 = ld8(bsh + kb);
            accz  = __builtin_amdgcn_mfma_f32_16x16x32_bf16(ahi, bz8, accz, 0, 0, 0);
            accr  = __builtin_amdgcn_mfma_f32_16x16x32_bf16(ahi, br8, accr, 0, 0, 0);
            accrh = __builtin_amdgcn_mfma_f32_16x16x32_bf16(ahi, bh8, accrh, 0, 0, 0);
            accz  = __builtin_amdgcn_mfma_f32_16x16x32_bf16(alo, bz8, accz, 0, 0, 0);
            accr  = __builtin_amdgcn_mfma_f32_16x16x32_bf16(alo, br8, accr, 0, 0, 0);
            accrh = __builtin_amdgcn_mfma_f32_16x16x32_bf16(alo, bh8, accrh, 0, 0, 0);
        }

        // epilogue: fast gates, update h, publish hi/lo
#pragma unroll
        for (int i = 0; i < 4; i++) {
            int rowc = g * 32 + rt * 16 + q * 4 + i;
            float z = fast_rcp(1.f + fast_exp(-(accz[i] + bzc)));
            float r = fast_rcp(1.f + fast_exp(-(accr[i] + brc)));
            float e2 = fast_exp(2.f * (accxh[i] + b0h + r * (accrh[i] + b1h)));
            float hh = 1.f - 2.f * fast_rcp(e2 + 1.f);
            float h = z * hown[i] + (1.f - z) * hh;
            if (j >= 700) h = 0.f;
            hown[i] = h;
            ushort_t hi = f2bf(h);
            Adst[rowc * AH_ROW + j] = hi;
            Adst[rowc * AH_ROW + HP + j] = f2bf(h - bf2f(hi));
        }

        // per-wave publish: drain own stores, then flag
        if (fast) {
            wave_drain();
            if (lane == 0)
                __hip_atomic_store(myflag, t + 2, __ATOMIC_RELAXED, __HIP_MEMORY_SCOPE_AGENT);
        } else {
            if (lane == 0)
                __hip_atomic_store(myflag, t + 2, __ATOMIC_RELEASE, __HIP_MEMORY_SCOPE_AGENT);
            else
                __threadfence();
        }
    }

    // ---- final output -------------------------------------------------------
#pragma unroll
    for (int i = 0; i < 4; i++) {
        int rowc = g * 32 + rt * 16 + q * 4 + i;
        if (j >= 200 && j < 700)
            out[rowc * 500 + (j - 200)] = hown[i];
    }
}

extern "C" void kernel_launch(void* const* d_in, const int* in_sizes, int n_in,
                              void* d_out, int out_size, void* d_ws, size_t ws_size,
                              hipStream_t stream) {
    (void)in_sizes; (void)n_in; (void)out_size; (void)ws_size;
    const int*   enc  = (const int*)d_in[0];
    const float* lab  = (const float*)d_in[1];
    const float* emb  = (const float*)d_in[2];
    const float* W1   = (const float*)d_in[3];
    const float* b1   = (const float*)d_in[4];
    const float* Wx   = (const float*)d_in[5];
    float*       Wh   = (float*)d_in[6];
    const float* bias = (const float*)d_in[7];

    int*   cnt = (int*)d_ws;               // 5.2 KB of scratch used
    float* out = (float*)d_out;

    init_cnt<<<1, 1024, 0, stream>>>(cnt);

    hipFuncSetAttribute((const void*)gru_main,
                        hipFuncAttributeMaxDynamicSharedMemorySize, 96 * SB * 2);
    gru_main<<<NBLK, 256, 96 * SB * 2, stream>>>(enc, emb, Wx, Wh, lab, W1, b1,
                                                 bias, out, cnt);
}

// Round 4
// 3784.372 us; speedup vs baseline: 1.1311x; 1.1311x over previous
//
#include <hip/hip_runtime.h>

// ---------------------------------------------------------------------------
// Encoder: x=emb[enc]; xp = x@Wx + b_in; reset-after GRU over T=256 steps;
// out = h_last[:, 200:700].  All float inputs fp32; output fp32.
//
// Persistent weight-stationary GRU, per-WAVE dataflow sync (R11):
//   - Consumer wave rt reads ONLY its own 16 rows, produced by same-rt waves
//     of the 22 producer blocks. Producer drains own stores (vmcnt(0) is
//     wave-local), publishes flag[g][slice][wave]; consumer polls 44 flags
//     lane-parallel. NO __syncthreads in the 256-step loop.
//   - 176 blocks; swizzle g=bx&7, s=bx>>3; HW_REG_XCC_ID check selects
//     fast (relaxed flags) or slow (release/acquire) per group.
//   - h fp32 in regs; exchanged as bf16 hi/lo pair through Wh buffer.
//   - d_ws: [8] grid barrier, [16..191] xcc, [256..1279] wave flags.
//   - R12: heaters on idle CUs = exact null -> DVFS-via-idle-CUs FALSIFIED.
//   - R13/R14 probe decode: no burn fired => fast=TRUE (bx%8 XCD mapping
//     holds). Dependent-FMA chain added its FULL nominal cost (+2.2ms =
//     8.6us/step = 4096 fma x ~5cyc at ~2.2-2.4GHz) => clock is FULL speed;
//     low-clock theory FALSIFIED. Lesson: symmetric insertion always adds
//     fully to the period, so the split of the ~20K-cyc/step period between
//     per-wave serial stalls (S) and publish->detect hop (h) is still
//     unknown; only ~2.8K cyc/step is MFMA+VALU issue, ~17K is s_waitcnt
//     stall with 1 wave/SIMD (zero latency hiding).
//   - R15 (this round): the largest unmeasured per-step term is l1_inv
//     (buffer_inv sc0) executed by all 4 waves/CU every step (cost unknown,
//     plausibly 1000s of cycles; also nukes enc/emb L1 locality each step).
//     ELIMINATE it: consumer A-data reads become relaxed AGENT-scope 8B
//     atomic loads (-> global_load_dwordx2 sc0: bypass L1, read L2
//     directly) — the same coherence the inv+plain pair provided. Flags
//     already use this mechanism. Producer side unchanged (drain vmcnt(0)
//     then relaxed flag store). Compiler barrier after the poll replaces
//     l1_inv's hoist-blocking role. sc0 loads also ignore stale staging-era
//     whf lines in L1. Slow path unchanged (acquire orders data loads).
//     Probe chain + burn removed.
// ---------------------------------------------------------------------------

typedef unsigned short ushort_t;
typedef unsigned long long u64;
typedef __bf16 bf16x8 __attribute__((ext_vector_type(8)));
typedef unsigned short ushort8 __attribute__((ext_vector_type(8)));
typedef float floatx4 __attribute__((ext_vector_type(4)));

#define NGRP   8
#define NSLC   22
#define NBLK   176
#define SB     840   // LDS row stride (bf16): 832 + 8 pad
#define HP     704
#define AH_ROW 1408  // hi[704] | lo[704]
#define PHASE  (256 * AH_ROW)
#define FLAGW(gg, ss, ww) (256 + (gg) * 128 + (ss) * 4 + (ww))

__device__ __forceinline__ float bf2f(ushort_t u) {
    unsigned v = ((unsigned)u) << 16; float f; __builtin_memcpy(&f, &v, 4); return f;
}
__device__ __forceinline__ ushort_t f2bf(float f) {
    unsigned u; __builtin_memcpy(&u, &f, 4);
    unsigned r = u + 0x7fff + ((u >> 16) & 1);
    return (ushort_t)(r >> 16);
}
__device__ __forceinline__ bf16x8 ld8(const ushort_t* p) {
    return __builtin_bit_cast(bf16x8, *(const ushort8*)p);
}
// agent-scope (sc0) 8B load: bypasses L1, reads L2 (coherence point).
__device__ __forceinline__ u64 lda8(const ushort_t* p) {
    return __hip_atomic_load((const u64*)p, __ATOMIC_RELAXED, __HIP_MEMORY_SCOPE_AGENT);
}
__device__ __forceinline__ bf16x8 mk8(u64 a, u64 b) {
    union { u64 q[2]; ushort8 v; } u;
    u.q[0] = a; u.q[1] = b;
    return __builtin_bit_cast(bf16x8, u.v);
}
__device__ __forceinline__ bf16x8 cvt8(floatx4 a, floatx4 b) {
    ushort8 r = {f2bf(a.x), f2bf(a.y), f2bf(a.z), f2bf(a.w),
                 f2bf(b.x), f2bf(b.y), f2bf(b.z), f2bf(b.w)};
    return __builtin_bit_cast(bf16x8, r);
}
__device__ __forceinline__ void wave_drain() {   // wave-local store drain
    asm volatile("s_waitcnt vmcnt(0)" ::: "memory");
}
__device__ __forceinline__ void compiler_fence() {
    asm volatile("" ::: "memory");
}
__device__ __forceinline__ float fast_rcp(float x) {
    float r; asm("v_rcp_f32 %0, %1" : "=v"(r) : "v"(x)); return r;
}
__device__ __forceinline__ float fast_exp(float x) {
    float r; asm("v_exp_f32 %0, %1" : "=v"(r) : "v"(x * 1.44269504f)); return r;
}

__global__ void init_cnt(int* cnt) {
    for (int i = threadIdx.x; i < 1280; i += 1024) cnt[i] = 0;
}

__global__ __launch_bounds__(256, 1) void gru_main(
    const int* __restrict__ enc, const float* __restrict__ emb,
    const float* __restrict__ Wx, float* whf,
    const float* __restrict__ lab, const float* __restrict__ W1,
    const float* __restrict__ b1, const float* __restrict__ bias,
    float* __restrict__ out, int* cnt) {

    extern __shared__ ushort_t Bs[];   // [96][SB] bf16
    const int bx = blockIdx.x;
    const int g = bx & 7, s = bx >> 3;
    const int tid = threadIdx.x;
    const int wave = tid >> 6, lane = tid & 63;
    const int rt = wave >> 1, ct = wave & 1;
    const int q = lane >> 4, m = lane & 15;

    // ---- one-time staging: Bs[p][k] = bf16(W[k][col(p)]), p = gate*32+c ----
    for (int idx = tid; idx < 96 * 832; idx += 256) {
        int p = idx % 96, k = idx / 96;
        int c = s * 32 + (p & 31);
        ushort_t v = 0;
        if (c < 700) {
            int col = (p >> 5) * 700 + c;
            if (k < 100) v = f2bf(Wx[k * 2100 + col]);
            else if (k >= 128 && k < 828) v = f2bf(whf[(k - 128) * 2100 + col]);
        }
        Bs[p * SB + k] = v;
    }
    __syncthreads();   // all Wh reads of this block retired

    // ---- publish xcc id, then grid barrier (agent scope, one-time) ---------
    if (tid == 0) {
        int xcc;
        asm("s_getreg_b32 %0, hwreg(HW_REG_XCC_ID)" : "=s"(xcc));
        __hip_atomic_store(cnt + 16 + bx, xcc, __ATOMIC_RELAXED, __HIP_MEMORY_SCOPE_AGENT);
        __hip_atomic_fetch_add(cnt + 8, 1, __ATOMIC_ACQ_REL, __HIP_MEMORY_SCOPE_AGENT);
        while (__hip_atomic_load(cnt + 8, __ATOMIC_ACQUIRE, __HIP_MEMORY_SCOPE_AGENT) < NBLK)
            __builtin_amdgcn_s_sleep(1);
    }
    __syncthreads();

    // ---- fast iff all 22 peers share an XCD --------------------------------
    bool fast = true;
    {
        int myx = __hip_atomic_load(cnt + 16 + bx, __ATOMIC_RELAXED, __HIP_MEMORY_SCOPE_AGENT);
        for (int s2 = 0; s2 < NSLC; ++s2) {
            int px = __hip_atomic_load(cnt + 16 + g + 8 * s2, __ATOMIC_RELAXED, __HIP_MEMORY_SCOPE_AGENT);
            fast = fast && (px == myx);
        }
    }

    const int j = s * 32 + ct * 16 + m;
    float bzc = 0.f, brc = 0.f, b0h = 0.f, b1h = 0.f;
    if (j < 700) {
        bzc = bias[j] + bias[2100 + j];
        brc = bias[700 + j] + bias[2800 + j];
        b0h = bias[1400 + j];
        b1h = bias[3500 + j];
    }
    const int rowa = g * 32 + rt * 16 + m;

    ushort_t* Ah = (ushort_t*)whf;
    int* myflag = cnt + FLAGW(g, s, wave);
    // consumer wave rt needs flags (s2, rt*2+ct') for s2=0..21, ct'=0..1
    int* pollp = (lane < 44)
               ? (cnt + FLAGW(g, lane >> 1, rt * 2 + (lane & 1)))
               : (int*)nullptr;

    // ---- h0; publish hi/lo to phase 0 (per-wave) ---------------------------
    float hown[4];
#pragma unroll
    for (int i = 0; i < 4; i++) {
        int rowc = g * 32 + rt * 16 + q * 4 + i;
        float v = 0.f;
        if (j < 200) v = lab[rowc] * W1[j] + b1[j];
        hown[i] = v;
        ushort_t hi = f2bf(v);
        Ah[rowc * AH_ROW + j] = hi;
        Ah[rowc * AH_ROW + HP + j] = f2bf(v - bf2f(hi));
    }
    if (fast) {
        wave_drain();
        if (lane == 0)
            __hip_atomic_store(myflag, 1, __ATOMIC_RELAXED, __HIP_MEMORY_SCOPE_AGENT);
    } else {
        if (lane == 0)
            __hip_atomic_store(myflag, 1, __ATOMIC_RELEASE, __HIP_MEMORY_SCOPE_AGENT);
        else
            __threadfence();
    }

    const ushort_t* bsz = Bs + (ct * 16 + m) * SB;
    const ushort_t* bsr = Bs + (32 + ct * 16 + m) * SB;
    const ushort_t* bsh = Bs + (64 + ct * 16 + m) * SB;

    // ---- initial x prefetch for t=0 ----------------------------------------
    floatx4 pf[6]; floatx4 pft;
    {
        int tok = enc[rowa * 256 + 0];
        const float* ep = emb + tok * 100;
#pragma unroll
        for (int kt = 0; kt < 3; ++kt) {
            pf[kt * 2]     = *(const floatx4*)(ep + kt * 32 + q * 8);
            pf[kt * 2 + 1] = *(const floatx4*)(ep + kt * 32 + q * 8 + 4);
        }
        pft = *(const floatx4*)(ep + 96);
    }

    for (int t = 0; t < 256; ++t) {
        const ushort_t* Asrc = Ah + (t & 1) * PHASE;
        ushort_t* Adst = Ah + ((t + 1) & 1) * PHASE;
        floatx4 accz = {0,0,0,0}, accr = {0,0,0,0}, accrh = {0,0,0,0}, accxh = {0,0,0,0};

        // x-part from prefetched registers (off the critical chain)
#pragma unroll
        for (int kt = 0; kt < 3; ++kt) {
            bf16x8 a = cvt8(pf[kt * 2], pf[kt * 2 + 1]);
            int kb = kt * 32 + q * 8;
            accz  = __builtin_amdgcn_mfma_f32_16x16x32_bf16(a, ld8(bsz + kb), accz, 0, 0, 0);
            accr  = __builtin_amdgcn_mfma_f32_16x16x32_bf16(a, ld8(bsr + kb), accr, 0, 0, 0);
            accxh = __builtin_amdgcn_mfma_f32_16x16x32_bf16(a, ld8(bsh + kb), accxh, 0, 0, 0);
        }
        {
            ushort8 t8 = {0, 0, 0, 0, 0, 0, 0, 0};
            if (q == 0) {
                t8[0] = f2bf(pft.x); t8[1] = f2bf(pft.y);
                t8[2] = f2bf(pft.z); t8[3] = f2bf(pft.w);
            }
            bf16x8 a = __builtin_bit_cast(bf16x8, t8);
            int kb = 96 + q * 8;
            accz  = __builtin_amdgcn_mfma_f32_16x16x32_bf16(a, ld8(bsz + kb), accz, 0, 0, 0);
            accr  = __builtin_amdgcn_mfma_f32_16x16x32_bf16(a, ld8(bsr + kb), accr, 0, 0, 0);
            accxh = __builtin_amdgcn_mfma_f32_16x16x32_bf16(a, ld8(bsh + kb), accxh, 0, 0, 0);
        }
        // prefetch x for t+1 (in flight during the wait)
        {
            int tn = (t < 255) ? t + 1 : 255;
            int tok = enc[rowa * 256 + tn];
            const float* ep = emb + tok * 100;
#pragma unroll
            for (int kt = 0; kt < 3; ++kt) {
                pf[kt * 2]     = *(const floatx4*)(ep + kt * 32 + q * 8);
                pf[kt * 2 + 1] = *(const floatx4*)(ep + kt * 32 + q * 8 + 4);
            }
            pft = *(const floatx4*)(ep + 96);
        }

        // wait (per-wave, lane-parallel over the 44 relevant producer waves)
        if (lane < 44) {
            if (fast) {
                int spin = 0;
                while (__hip_atomic_load(pollp, __ATOMIC_RELAXED, __HIP_MEMORY_SCOPE_AGENT) < t + 1) {
                    if (++spin > 64) __builtin_amdgcn_s_sleep(1);
                }
            } else {
                while (__hip_atomic_load(pollp, __ATOMIC_ACQUIRE, __HIP_MEMORY_SCOPE_AGENT) < t + 1)
                    __builtin_amdgcn_s_sleep(1);
            }
        }
        compiler_fence();   // keep A-loads below the poll (replaces l1_inv's barrier role)

        // h-part: 22 K-tiles; ring-buffer prefetch depth 8 of hi/lo A-frags,
        // loaded as agent-scope (sc0) 8B pairs — L1 bypassed, no inv needed.
        const ushort_t* arow = Asrc + rowa * AH_ROW + q * 8;
        u64 ra0[8], ra1[8], rb0[8], rb1[8];
#pragma unroll
        for (int p = 0; p < 8; ++p) {
            ra0[p] = lda8(arow + p * 32);
            ra1[p] = lda8(arow + p * 32 + 4);
            rb0[p] = lda8(arow + HP + p * 32);
            rb1[p] = lda8(arow + HP + p * 32 + 4);
        }
#pragma unroll
        for (int kt = 0; kt < 22; ++kt) {
            bf16x8 ahi = mk8(ra0[kt & 7], ra1[kt & 7]);
            bf16x8 alo = mk8(rb0[kt & 7], rb1[kt & 7]);
            if (kt + 8 < 22) {
                const ushort_t* pp = arow + (kt + 8) * 32;
                ra0[kt & 7] = lda8(pp);
                ra1[kt & 7] = lda8(pp + 4);
                rb0[kt & 7] = lda8(pp + HP);
                rb1[kt & 7] = lda8(pp + HP + 4);
            }
            int kb = 128 + kt * 32 + q * 8;
            bf16x8 bz8 = ld8(bsz + kb), br8 = ld8(bsr + kb), bh8 = ld8(bsh + kb);
            accz  = __builtin_amdgcn_mfma_f32_16x16x32_bf16(ahi, bz8, accz, 0, 0, 0);
            accr  = __builtin_amdgcn_mfma_f32_16x16x32_bf16(ahi, br8, accr, 0, 0, 0);
            accrh = __builtin_amdgcn_mfma_f32_16x16x32_bf16(ahi, bh8, accrh, 0, 0, 0);
            accz  = __builtin_amdgcn_mfma_f32_16x16x32_bf16(alo, bz8, accz, 0, 0, 0);
            accr  = __builtin_amdgcn_mfma_f32_16x16x32_bf16(alo, br8, accr, 0, 0, 0);
            accrh = __builtin_amdgcn_mfma_f32_16x16x32_bf16(alo, bh8, accrh, 0, 0, 0);
        }

        // epilogue: fast gates, update h, publish hi/lo
#pragma unroll
        for (int i = 0; i < 4; i++) {
            int rowc = g * 32 + rt * 16 + q * 4 + i;
            float z = fast_rcp(1.f + fast_exp(-(accz[i] + bzc)));
            float r = fast_rcp(1.f + fast_exp(-(accr[i] + brc)));
            float e2 = fast_exp(2.f * (accxh[i] + b0h + r * (accrh[i] + b1h)));
            float hh = 1.f - 2.f * fast_rcp(e2 + 1.f);
            float h = z * hown[i] + (1.f - z) * hh;
            if (j >= 700) h = 0.f;
            hown[i] = h;
            ushort_t hi = f2bf(h);
            Adst[rowc * AH_ROW + j] = hi;
            Adst[rowc * AH_ROW + HP + j] = f2bf(h - bf2f(hi));
        }

        // per-wave publish: drain own stores, then flag
        if (fast) {
            wave_drain();
            if (lane == 0)
                __hip_atomic_store(myflag, t + 2, __ATOMIC_RELAXED, __HIP_MEMORY_SCOPE_AGENT);
        } else {
            if (lane == 0)
                __hip_atomic_store(myflag, t + 2, __ATOMIC_RELEASE, __HIP_MEMORY_SCOPE_AGENT);
            else
                __threadfence();
        }
    }

    // ---- final output -------------------------------------------------------
#pragma unroll
    for (int i = 0; i < 4; i++) {
        int rowc = g * 32 + rt * 16 + q * 4 + i;
        if (j >= 200 && j < 700)
            out[rowc * 500 + (j - 200)] = hown[i];
    }
}

extern "C" void kernel_launch(void* const* d_in, const int* in_sizes, int n_in,
                              void* d_out, int out_size, void* d_ws, size_t ws_size,
                              hipStream_t stream) {
    (void)in_sizes; (void)n_in; (void)out_size; (void)ws_size;
    const int*   enc  = (const int*)d_in[0];
    const float* lab  = (const float*)d_in[1];
    const float* emb  = (const float*)d_in[2];
    const float* W1   = (const float*)d_in[3];
    const float* b1   = (const float*)d_in[4];
    const float* Wx   = (const float*)d_in[5];
    float*       Wh   = (float*)d_in[6];
    const float* bias = (const float*)d_in[7];

    int*   cnt = (int*)d_ws;               // 5.2 KB of scratch used
    float* out = (float*)d_out;

    init_cnt<<<1, 1024, 0, stream>>>(cnt);

    hipFuncSetAttribute((const void*)gru_main,
                        hipFuncAttributeMaxDynamicSharedMemorySize, 96 * SB * 2);
    gru_main<<<NBLK, 256, 96 * SB * 2, stream>>>(enc, emb, Wx, Wh, lab, W1, b1,
                                                 bias, out, cnt);
}

// Round 6
// 3753.261 us; speedup vs baseline: 1.1404x; 1.0083x over previous
//
#include <hip/hip_runtime.h>

// ---------------------------------------------------------------------------
// Encoder: x=emb[enc]; xp = x@Wx + b_in; reset-after GRU over T=256 steps;
// out = h_last[:, 200:700].  All float inputs fp32; output fp32.
//
// Persistent weight-stationary GRU, per-WAVE dataflow sync:
//   - Consumer wave rt reads ONLY its own 16 rows, produced by same-rt waves
//     of the 22 producer blocks. Producer drains own stores (vmcnt(0) is
//     wave-local) then publishes flag[g][slice][wave]; consumer polls its 44
//     flags lane-parallel. NO __syncthreads in the 256-step loop.
//   - 176 blocks; swizzle g=bx&7, s=bx>>3; HW_REG_XCC_ID check selects fast
//     (same-XCD group) or slow (release/acquire agent) per group.
//   - h fp32 in regs; exchanged as bf16 hi/lo pair through Wh buffer (dead
//     after staging); A-reads = l1_inv + plain b128 ring (L2-coherent).
//   - d_ws: [8] grid barrier, [16..191] xcc, [256..2303] flags: per group g,
//     256 ints at 256+g*256: [0..87] sc0 flags, [128..215] agent mirrors.
//     init_cnt zeroes 2304 ints (9.2 KB).
//
// Evidence ledger:
//   - R12: VALU heaters on the 80 idle CUs = exact null -> DVFS theory dead.
//   - R13: fast=TRUE (no burn); dependent-FMA chain added FULL nominal cost
//     -> full clock; ~20K cyc/step = per-wave serial S + publish->detect h,
//     only ~2.8K is issue.
//   - R15: A-loads as relaxed AGENT atomics = +6.6us/step REGRESSION.
//     Learning: agent scope on gfx950 = sc0+sc1 = bypass L1 AND L2 (XCD L2s
//     not cross-coherent; agent coherence point = L3). So baseline flag
//     polls/stores are ~900/~700-cyc L3 round trips every step. R8's old
//     "sc0-load falsified" was a mixed-level pair (agent store + sc0 load),
//     not evidence against sc0 BOTH sides.
//   - R16: flags -> sc0 both sides (XCD-L2 coherence; h-data path already
//     proves plain/L2 exchange works within a group) + x-prefetch moved
//     after the poll (baseline's first poll vmcnt(0) drained the emb gather
//     ~1-1.6K cyc into the critical path). Bench died in the harness
//     (Trio nursery) — infra flake OR sc0-visibility hang; no signal.
//   - R17 (this round) = R16 + HANG INSURANCE: producer also stores an
//     agent-scope MIRROR word (separate line, off critical path) after the
//     same drain; consumer polls sc0 tight and after 64 spins also accepts
//     the mirror. sc0 working => mirror never consulted (64 sc0 polls
//     ~19K cyc >> steady-state arrival). sc0 broken => degrades to
//     ~baseline agent polling instead of hanging. Either way: signal.
// ---------------------------------------------------------------------------

typedef unsigned short ushort_t;
typedef __bf16 bf16x8 __attribute__((ext_vector_type(8)));
typedef unsigned short ushort8 __attribute__((ext_vector_type(8)));
typedef float floatx4 __attribute__((ext_vector_type(4)));

#define NGRP   8
#define NSLC   22
#define NBLK   176
#define SB     840   // LDS row stride (bf16): 832 + 8 pad
#define HP     704
#define AH_ROW 1408  // hi[704] | lo[704]
#define PHASE  (256 * AH_ROW)
#define FLAGW(gg, ss, ww) (256 + (gg) * 256 + (ss) * 4 + (ww))
#define MIRROFF 128   // agent-scope mirror offset within a group's region

__device__ __forceinline__ float bf2f(ushort_t u) {
    unsigned v = ((unsigned)u) << 16; float f; __builtin_memcpy(&f, &v, 4); return f;
}
__device__ __forceinline__ ushort_t f2bf(float f) {
    unsigned u; __builtin_memcpy(&u, &f, 4);
    unsigned r = u + 0x7fff + ((u >> 16) & 1);
    return (ushort_t)(r >> 16);
}
__device__ __forceinline__ bf16x8 ld8(const ushort_t* p) {
    return __builtin_bit_cast(bf16x8, *(const ushort8*)p);
}
__device__ __forceinline__ bf16x8 cvt8(floatx4 a, floatx4 b) {
    ushort8 r = {f2bf(a.x), f2bf(a.y), f2bf(a.z), f2bf(a.w),
                 f2bf(b.x), f2bf(b.y), f2bf(b.z), f2bf(b.w)};
    return __builtin_bit_cast(bf16x8, r);
}
__device__ __forceinline__ void l1_inv() {
    asm volatile("buffer_inv sc0" ::: "memory");
}
__device__ __forceinline__ void wave_drain() {   // wave-local store drain
    asm volatile("s_waitcnt vmcnt(0)" ::: "memory");
}
// XCD-L2 coherent flag ops (fast path only): sc0 = bypass L1, hit shared L2.
__device__ __forceinline__ void flag_store_sc0(int* p, int v) {
    asm volatile("global_store_dword %0, %1, off sc0" :: "v"(p), "v"(v) : "memory");
}
__device__ __forceinline__ int flag_load_sc0(const int* p) {
    int v;
    asm volatile("global_load_dword %0, %1, off sc0\n\t"
                 "s_waitcnt vmcnt(0)"
                 : "=v"(v) : "v"(p) : "memory");
    return v;
}
__device__ __forceinline__ float fast_rcp(float x) {
    float r; asm("v_rcp_f32 %0, %1" : "=v"(r) : "v"(x)); return r;
}
__device__ __forceinline__ float fast_exp(float x) {
    float r; asm("v_exp_f32 %0, %1" : "=v"(r) : "v"(x * 1.44269504f)); return r;
}

__global__ void init_cnt(int* cnt) {
    for (int i = threadIdx.x; i < 2304; i += 1024) cnt[i] = 0;
}

__global__ __launch_bounds__(256, 1) void gru_main(
    const int* __restrict__ enc, const float* __restrict__ emb,
    const float* __restrict__ Wx, float* whf,
    const float* __restrict__ lab, const float* __restrict__ W1,
    const float* __restrict__ b1, const float* __restrict__ bias,
    float* __restrict__ out, int* cnt) {

    extern __shared__ ushort_t Bs[];   // [96][SB] bf16
    const int bx = blockIdx.x;
    const int g = bx & 7, s = bx >> 3;
    const int tid = threadIdx.x;
    const int wave = tid >> 6, lane = tid & 63;
    const int rt = wave >> 1, ct = wave & 1;
    const int q = lane >> 4, m = lane & 15;

    // ---- one-time staging: Bs[p][k] = bf16(W[k][col(p)]), p = gate*32+c ----
    for (int idx = tid; idx < 96 * 832; idx += 256) {
        int p = idx % 96, k = idx / 96;
        int c = s * 32 + (p & 31);
        ushort_t v = 0;
        if (c < 700) {
            int col = (p >> 5) * 700 + c;
            if (k < 100) v = f2bf(Wx[k * 2100 + col]);
            else if (k >= 128 && k < 828) v = f2bf(whf[(k - 128) * 2100 + col]);
        }
        Bs[p * SB + k] = v;
    }
    __syncthreads();   // all Wh reads of this block retired

    // ---- publish xcc id, then grid barrier (agent scope, one-time) ---------
    if (tid == 0) {
        int xcc;
        asm("s_getreg_b32 %0, hwreg(HW_REG_XCC_ID)" : "=s"(xcc));
        __hip_atomic_store(cnt + 16 + bx, xcc, __ATOMIC_RELAXED, __HIP_MEMORY_SCOPE_AGENT);
        __hip_atomic_fetch_add(cnt + 8, 1, __ATOMIC_ACQ_REL, __HIP_MEMORY_SCOPE_AGENT);
        while (__hip_atomic_load(cnt + 8, __ATOMIC_ACQUIRE, __HIP_MEMORY_SCOPE_AGENT) < NBLK)
            __builtin_amdgcn_s_sleep(1);
    }
    __syncthreads();

    // ---- fast iff all 22 peers share an XCD --------------------------------
    bool fast = true;
    {
        int myx = __hip_atomic_load(cnt + 16 + bx, __ATOMIC_RELAXED, __HIP_MEMORY_SCOPE_AGENT);
        for (int s2 = 0; s2 < NSLC; ++s2) {
            int px = __hip_atomic_load(cnt + 16 + g + 8 * s2, __ATOMIC_RELAXED, __HIP_MEMORY_SCOPE_AGENT);
            fast = fast && (px == myx);
        }
    }

    const int j = s * 32 + ct * 16 + m;
    float bzc = 0.f, brc = 0.f, b0h = 0.f, b1h = 0.f;
    if (j < 700) {
        bzc = bias[j] + bias[2100 + j];
        brc = bias[700 + j] + bias[2800 + j];
        b0h = bias[1400 + j];
        b1h = bias[3500 + j];
    }
    const int rowa = g * 32 + rt * 16 + m;

    ushort_t* Ah = (ushort_t*)whf;
    int* myflag = cnt + FLAGW(g, s, wave);
    int* mymirr = myflag + MIRROFF;
    // consumer wave rt needs flags (s2, rt*2+ct') for s2=0..21, ct'=0..1
    int* pollp = (lane < 44)
               ? (cnt + FLAGW(g, lane >> 1, rt * 2 + (lane & 1)))
               : (int*)nullptr;
    int* pollm = pollp ? pollp + MIRROFF : (int*)nullptr;

    // ---- h0; publish hi/lo to phase 0 (per-wave) ---------------------------
    float hown[4];
#pragma unroll
    for (int i = 0; i < 4; i++) {
        int rowc = g * 32 + rt * 16 + q * 4 + i;
        float v = 0.f;
        if (j < 200) v = lab[rowc] * W1[j] + b1[j];
        hown[i] = v;
        ushort_t hi = f2bf(v);
        Ah[rowc * AH_ROW + j] = hi;
        Ah[rowc * AH_ROW + HP + j] = f2bf(v - bf2f(hi));
    }
    if (fast) {
        wave_drain();
        if (lane == 0) {
            flag_store_sc0(myflag, 1);
            __hip_atomic_store(mymirr, 1, __ATOMIC_RELAXED, __HIP_MEMORY_SCOPE_AGENT);
        }
    } else {
        if (lane == 0)
            __hip_atomic_store(myflag, 1, __ATOMIC_RELEASE, __HIP_MEMORY_SCOPE_AGENT);
        else
            __threadfence();
    }

    const ushort_t* bsz = Bs + (ct * 16 + m) * SB;
    const ushort_t* bsr = Bs + (32 + ct * 16 + m) * SB;
    const ushort_t* bsh = Bs + (64 + ct * 16 + m) * SB;

    // ---- initial x prefetch for t=0 ----------------------------------------
    floatx4 pf[6]; floatx4 pft;
    {
        int tok = enc[rowa * 256 + 0];
        const float* ep = emb + tok * 100;
#pragma unroll
        for (int kt = 0; kt < 3; ++kt) {
            pf[kt * 2]     = *(const floatx4*)(ep + kt * 32 + q * 8);
            pf[kt * 2 + 1] = *(const floatx4*)(ep + kt * 32 + q * 8 + 4);
        }
        pft = *(const floatx4*)(ep + 96);
    }

    for (int t = 0; t < 256; ++t) {
        const ushort_t* Asrc = Ah + (t & 1) * PHASE;
        ushort_t* Adst = Ah + ((t + 1) & 1) * PHASE;
        floatx4 accz = {0,0,0,0}, accr = {0,0,0,0}, accrh = {0,0,0,0}, accxh = {0,0,0,0};

        // x-part from prefetched registers (off the critical chain)
#pragma unroll
        for (int kt = 0; kt < 3; ++kt) {
            bf16x8 a = cvt8(pf[kt * 2], pf[kt * 2 + 1]);
            int kb = kt * 32 + q * 8;
            accz  = __builtin_amdgcn_mfma_f32_16x16x32_bf16(a, ld8(bsz + kb), accz, 0, 0, 0);
            accr  = __builtin_amdgcn_mfma_f32_16x16x32_bf16(a, ld8(bsr + kb), accr, 0, 0, 0);
            accxh = __builtin_amdgcn_mfma_f32_16x16x32_bf16(a, ld8(bsh + kb), accxh, 0, 0, 0);
        }
        {
            ushort8 t8 = {0, 0, 0, 0, 0, 0, 0, 0};
            if (q == 0) {
                t8[0] = f2bf(pft.x); t8[1] = f2bf(pft.y);
                t8[2] = f2bf(pft.z); t8[3] = f2bf(pft.w);
            }
            bf16x8 a = __builtin_bit_cast(bf16x8, t8);
            int kb = 96 + q * 8;
            accz  = __builtin_amdgcn_mfma_f32_16x16x32_bf16(a, ld8(bsz + kb), accz, 0, 0, 0);
            accr  = __builtin_amdgcn_mfma_f32_16x16x32_bf16(a, ld8(bsr + kb), accr, 0, 0, 0);
            accxh = __builtin_amdgcn_mfma_f32_16x16x32_bf16(a, ld8(bsh + kb), accxh, 0, 0, 0);
        }

        // wait (per-wave, lane-parallel over the 44 relevant producer waves).
        // Poll enters with ZERO outstanding vmem (x-prefetch moved below):
        // each iteration is a pure sc0 flag round trip (~L2 latency).
        // After 64 spins, also accept the agent-scope mirror (hang insurance;
        // never consulted when sc0 coherence works).
        if (lane < 44) {
            if (fast) {
                int spin = 0;
                while (flag_load_sc0(pollp) < t + 1) {
                    if (++spin > 64) {
                        if (__hip_atomic_load(pollm, __ATOMIC_RELAXED,
                                              __HIP_MEMORY_SCOPE_AGENT) >= t + 1)
                            break;
                        __builtin_amdgcn_s_sleep(1);
                    }
                }
            } else {
                while (__hip_atomic_load(pollp, __ATOMIC_ACQUIRE, __HIP_MEMORY_SCOPE_AGENT) < t + 1)
                    __builtin_amdgcn_s_sleep(1);
            }
        }
        if (fast) l1_inv();   // fresh L1 for this wave's h reads

        // prefetch x for t+1 (issued here so its L3/HBM latency hides under
        // the A-ring + MFMA region instead of the poll's vmcnt(0))
        {
            int tn = (t < 255) ? t + 1 : 255;
            int tok = enc[rowa * 256 + tn];
            const float* ep = emb + tok * 100;
#pragma unroll
            for (int kt = 0; kt < 3; ++kt) {
                pf[kt * 2]     = *(const floatx4*)(ep + kt * 32 + q * 8);
                pf[kt * 2 + 1] = *(const floatx4*)(ep + kt * 32 + q * 8 + 4);
            }
            pft = *(const floatx4*)(ep + 96);
        }

        // h-part: 22 K-tiles; ring-buffer prefetch depth 8 of hi/lo A-frags
        const ushort_t* arow = Asrc + rowa * AH_ROW + q * 8;
        bf16x8 ra[8], rb[8];
#pragma unroll
        for (int p = 0; p < 8; ++p) {
            ra[p] = ld8(arow + p * 32);
            rb[p] = ld8(arow + HP + p * 32);
        }
#pragma unroll
        for (int kt = 0; kt < 22; ++kt) {
            bf16x8 ahi = ra[kt & 7];
            bf16x8 alo = rb[kt & 7];
            if (kt + 8 < 22) {
                ra[kt & 7] = ld8(arow + (kt + 8) * 32);
                rb[kt & 7] = ld8(arow + HP + (kt + 8) * 32);
            }
            int kb = 128 + kt * 32 + q * 8;
            bf16x8 bz8 = ld8(bsz + kb), br8 = ld8(bsr + kb), bh8 = ld8(bsh + kb);
            accz  = __builtin_amdgcn_mfma_f32_16x16x32_bf16(ahi, bz8, accz, 0, 0, 0);
            accr  = __builtin_amdgcn_mfma_f32_16x16x32_bf16(ahi, br8, accr, 0, 0, 0);
            accrh = __builtin_amdgcn_mfma_f32_16x16x32_bf16(ahi, bh8, accrh, 0, 0, 0);
            accz  = __builtin_amdgcn_mfma_f32_16x16x32_bf16(alo, bz8, accz, 0, 0, 0);
            accr  = __builtin_amdgcn_mfma_f32_16x16x32_bf16(alo, br8, accr, 0, 0, 0);
            accrh = __builtin_amdgcn_mfma_f32_16x16x32_bf16(alo, bh8, accrh, 0, 0, 0);
        }

        // epilogue: fast gates, update h, publish hi/lo
#pragma unroll
        for (int i = 0; i < 4; i++) {
            int rowc = g * 32 + rt * 16 + q * 4 + i;
            float z = fast_rcp(1.f + fast_exp(-(accz[i] + bzc)));
            float r = fast_rcp(1.f + fast_exp(-(accr[i] + brc)));
            float e2 = fast_exp(2.f * (accxh[i] + b0h + r * (accrh[i] + b1h)));
            float hh = 1.f - 2.f * fast_rcp(e2 + 1.f);
            float h = z * hown[i] + (1.f - z) * hh;
            if (j >= 700) h = 0.f;
            hown[i] = h;
            ushort_t hi = f2bf(h);
            Adst[rowc * AH_ROW + j] = hi;
            Adst[rowc * AH_ROW + HP + j] = f2bf(h - bf2f(hi));
        }

        // per-wave publish: drain own stores, then flag (sc0 + agent mirror)
        if (fast) {
            wave_drain();
            if (lane == 0) {
                flag_store_sc0(myflag, t + 2);
                __hip_atomic_store(mymirr, t + 2, __ATOMIC_RELAXED, __HIP_MEMORY_SCOPE_AGENT);
            }
        } else {
            if (lane == 0)
                __hip_atomic_store(myflag, t + 2, __ATOMIC_RELEASE, __HIP_MEMORY_SCOPE_AGENT);
            else
                __threadfence();
        }
    }

    // ---- final output -------------------------------------------------------
#pragma unroll
    for (int i = 0; i < 4; i++) {
        int rowc = g * 32 + rt * 16 + q * 4 + i;
        if (j >= 200 && j < 700)
            out[rowc * 500 + (j - 200)] = hown[i];
    }
}

extern "C" void kernel_launch(void* const* d_in, const int* in_sizes, int n_in,
                              void* d_out, int out_size, void* d_ws, size_t ws_size,
                              hipStream_t stream) {
    (void)in_sizes; (void)n_in; (void)out_size; (void)ws_size;
    const int*   enc  = (const int*)d_in[0];
    const float* lab  = (const float*)d_in[1];
    const float* emb  = (const float*)d_in[2];
    const float* W1   = (const float*)d_in[3];
    const float* b1   = (const float*)d_in[4];
    const float* Wx   = (const float*)d_in[5];
    float*       Wh   = (float*)d_in[6];
    const float* bias = (const float*)d_in[7];

    int*   cnt = (int*)d_ws;               // 9.2 KB of scratch used
    float* out = (float*)d_out;

    init_cnt<<<1, 1024, 0, stream>>>(cnt);

    hipFuncSetAttribute((const void*)gru_main,
                        hipFuncAttributeMaxDynamicSharedMemorySize, 96 * SB * 2);
    gru_main<<<NBLK, 256, 96 * SB * 2, stream>>>(enc, emb, Wx, Wh, lab, W1, b1,
                                                 bias, out, cnt);
}

// Round 7
// 2323.151 us; speedup vs baseline: 1.8425x; 1.6156x over previous
//
#include <hip/hip_runtime.h>

// ---------------------------------------------------------------------------
// Encoder: x=emb[enc]; xp = x@Wx + b_in; reset-after GRU over T=256 steps;
// out = h_last[:, 200:700].  All float inputs fp32; output fp32.
//
// Persistent weight-stationary GRU, per-WAVE dataflow sync (R11 fabric):
//   - Consumer wave rt reads ONLY its own 16 rows, produced by same-rt waves
//     of the 22 producer blocks. Producer drains own stores (vmcnt(0) is
//     wave-local) then publishes flag[g][slice][wave] (relaxed agent store);
//     consumer polls its 44 flags lane-parallel (relaxed agent loads), then
//     l1_inv + plain b128 A-ring. NO __syncthreads in the 256-step loop.
//   - 176 blocks; swizzle g=bx&7, s=bx>>3; HW_REG_XCC_ID check selects fast
//     (same-XCD group) or slow (release/acquire agent) per group.
//   - d_ws: [8] grid barrier, [16..191] xcc, [256..1279] wave flags
//     (128-int groups); init_cnt zeroes 1280 ints.
//
// Evidence ledger:
//   - R12: VALU heaters on 80 idle CUs = exact null -> DVFS theory dead.
//   - R13: fast=TRUE (no burn); dependent-FMA chain added FULL nominal cost
//     -> full (or near-full) clock; ~20K cyc/step = serial S + publish->
//     detect hop h; only ~2.8K is issue.
//   - R15: A-loads as relaxed AGENT atomics = big regression. Agent scope on
//     gfx950 = bypass L1 AND L2 (XCD L2s not cross-coherent; coherence point
//     = L3/MALL).
//   - R17: sc0-only flags (both sides) NEVER observed by the consumer --
//     completed only via agent mirror fallback (+64 wasted sc0 spins/step).
//     With R8: sc0-only observation is triple-falsified. There is NO cheap
//     L2-level cross-block observation primitive; agent (L3) atomics or
//     l1_inv+plain are the only working paths. sc0/mirror machinery deleted.
//   - R18 (this round): revert to the proven R11 fabric; KEEP the R16
//     x-prefetch-after-poll reorder (baseline drained the emb gather into
//     the critical path at the first poll iteration's vmcnt(0)).
//     PROBE: 4 chained address-dependent agent-atomic loads per step on
//     lane0 of EVERY wave, inserted after the flag publish => period grows
//     by exactly 4 x RT_agent. Decode from dur: ~+380us => RT~900cyc (flag
//     hop is minor; attack the data plane next); ~+1.3-2.1ms => RT~2.5-4Kcyc
//     (publish->detect hop dominates; redesign observation next).
// ---------------------------------------------------------------------------

typedef unsigned short ushort_t;
typedef __bf16 bf16x8 __attribute__((ext_vector_type(8)));
typedef unsigned short ushort8 __attribute__((ext_vector_type(8)));
typedef float floatx4 __attribute__((ext_vector_type(4)));

#define NGRP   8
#define NSLC   22
#define NBLK   176
#define SB     840   // LDS row stride (bf16): 832 + 8 pad
#define HP     704
#define AH_ROW 1408  // hi[704] | lo[704]
#define PHASE  (256 * AH_ROW)
#define FLAGW(gg, ss, ww) (256 + (gg) * 128 + (ss) * 4 + (ww))

__device__ __forceinline__ float bf2f(ushort_t u) {
    unsigned v = ((unsigned)u) << 16; float f; __builtin_memcpy(&f, &v, 4); return f;
}
__device__ __forceinline__ ushort_t f2bf(float f) {
    unsigned u; __builtin_memcpy(&u, &f, 4);
    unsigned r = u + 0x7fff + ((u >> 16) & 1);
    return (ushort_t)(r >> 16);
}
__device__ __forceinline__ bf16x8 ld8(const ushort_t* p) {
    return __builtin_bit_cast(bf16x8, *(const ushort8*)p);
}
__device__ __forceinline__ bf16x8 cvt8(floatx4 a, floatx4 b) {
    ushort8 r = {f2bf(a.x), f2bf(a.y), f2bf(a.z), f2bf(a.w),
                 f2bf(b.x), f2bf(b.y), f2bf(b.z), f2bf(b.w)};
    return __builtin_bit_cast(bf16x8, r);
}
__device__ __forceinline__ void l1_inv() {
    asm volatile("buffer_inv sc0" ::: "memory");
}
__device__ __forceinline__ void wave_drain() {   // wave-local store drain
    asm volatile("s_waitcnt vmcnt(0)" ::: "memory");
}
__device__ __forceinline__ float fast_rcp(float x) {
    float r; asm("v_rcp_f32 %0, %1" : "=v"(r) : "v"(x)); return r;
}
__device__ __forceinline__ float fast_exp(float x) {
    float r; asm("v_exp_f32 %0, %1" : "=v"(r) : "v"(x * 1.44269504f)); return r;
}

__global__ void init_cnt(int* cnt) {
    for (int i = threadIdx.x; i < 1280; i += 1024) cnt[i] = 0;
}

__global__ __launch_bounds__(256, 1) void gru_main(
    const int* __restrict__ enc, const float* __restrict__ emb,
    const float* __restrict__ Wx, float* whf,
    const float* __restrict__ lab, const float* __restrict__ W1,
    const float* __restrict__ b1, const float* __restrict__ bias,
    float* __restrict__ out, int* cnt) {

    extern __shared__ ushort_t Bs[];   // [96][SB] bf16
    const int bx = blockIdx.x;
    const int g = bx & 7, s = bx >> 3;
    const int tid = threadIdx.x;
    const int wave = tid >> 6, lane = tid & 63;
    const int rt = wave >> 1, ct = wave & 1;
    const int q = lane >> 4, m = lane & 15;

    // ---- one-time staging: Bs[p][k] = bf16(W[k][col(p)]), p = gate*32+c ----
    for (int idx = tid; idx < 96 * 832; idx += 256) {
        int p = idx % 96, k = idx / 96;
        int c = s * 32 + (p & 31);
        ushort_t v = 0;
        if (c < 700) {
            int col = (p >> 5) * 700 + c;
            if (k < 100) v = f2bf(Wx[k * 2100 + col]);
            else if (k >= 128 && k < 828) v = f2bf(whf[(k - 128) * 2100 + col]);
        }
        Bs[p * SB + k] = v;
    }
    __syncthreads();   // all Wh reads of this block retired

    // ---- publish xcc id, then grid barrier (agent scope, one-time) ---------
    if (tid == 0) {
        int xcc;
        asm("s_getreg_b32 %0, hwreg(HW_REG_XCC_ID)" : "=s"(xcc));
        __hip_atomic_store(cnt + 16 + bx, xcc, __ATOMIC_RELAXED, __HIP_MEMORY_SCOPE_AGENT);
        __hip_atomic_fetch_add(cnt + 8, 1, __ATOMIC_ACQ_REL, __HIP_MEMORY_SCOPE_AGENT);
        while (__hip_atomic_load(cnt + 8, __ATOMIC_ACQUIRE, __HIP_MEMORY_SCOPE_AGENT) < NBLK)
            __builtin_amdgcn_s_sleep(1);
    }
    __syncthreads();

    // ---- fast iff all 22 peers share an XCD --------------------------------
    bool fast = true;
    {
        int myx = __hip_atomic_load(cnt + 16 + bx, __ATOMIC_RELAXED, __HIP_MEMORY_SCOPE_AGENT);
        for (int s2 = 0; s2 < NSLC; ++s2) {
            int px = __hip_atomic_load(cnt + 16 + g + 8 * s2, __ATOMIC_RELAXED, __HIP_MEMORY_SCOPE_AGENT);
            fast = fast && (px == myx);
        }
    }

    const int j = s * 32 + ct * 16 + m;
    float bzc = 0.f, brc = 0.f, b0h = 0.f, b1h = 0.f;
    if (j < 700) {
        bzc = bias[j] + bias[2100 + j];
        brc = bias[700 + j] + bias[2800 + j];
        b0h = bias[1400 + j];
        b1h = bias[3500 + j];
    }
    const int rowa = g * 32 + rt * 16 + m;

    ushort_t* Ah = (ushort_t*)whf;
    int* myflag = cnt + FLAGW(g, s, wave);
    // consumer wave rt needs flags (s2, rt*2+ct') for s2=0..21, ct'=0..1
    int* pollp = (lane < 44)
               ? (cnt + FLAGW(g, lane >> 1, rt * 2 + (lane & 1)))
               : (int*)nullptr;
    // probe target: far group's flag word (read-only, always present)
    const int* probep = cnt + FLAGW(g ^ 1, s, wave);

    // ---- h0; publish hi/lo to phase 0 (per-wave) ---------------------------
    float hown[4];
#pragma unroll
    for (int i = 0; i < 4; i++) {
        int rowc = g * 32 + rt * 16 + q * 4 + i;
        float v = 0.f;
        if (j < 200) v = lab[rowc] * W1[j] + b1[j];
        hown[i] = v;
        ushort_t hi = f2bf(v);
        Ah[rowc * AH_ROW + j] = hi;
        Ah[rowc * AH_ROW + HP + j] = f2bf(v - bf2f(hi));
    }
    if (fast) {
        wave_drain();
        if (lane == 0)
            __hip_atomic_store(myflag, 1, __ATOMIC_RELAXED, __HIP_MEMORY_SCOPE_AGENT);
    } else {
        if (lane == 0)
            __hip_atomic_store(myflag, 1, __ATOMIC_RELEASE, __HIP_MEMORY_SCOPE_AGENT);
        else
            __threadfence();
    }

    const ushort_t* bsz = Bs + (ct * 16 + m) * SB;
    const ushort_t* bsr = Bs + (32 + ct * 16 + m) * SB;
    const ushort_t* bsh = Bs + (64 + ct * 16 + m) * SB;

    // ---- initial x prefetch for t=0 ----------------------------------------
    floatx4 pf[6]; floatx4 pft;
    {
        int tok = enc[rowa * 256 + 0];
        const float* ep = emb + tok * 100;
#pragma unroll
        for (int kt = 0; kt < 3; ++kt) {
            pf[kt * 2]     = *(const floatx4*)(ep + kt * 32 + q * 8);
            pf[kt * 2 + 1] = *(const floatx4*)(ep + kt * 32 + q * 8 + 4);
        }
        pft = *(const floatx4*)(ep + 96);
    }

    for (int t = 0; t < 256; ++t) {
        const ushort_t* Asrc = Ah + (t & 1) * PHASE;
        ushort_t* Adst = Ah + ((t + 1) & 1) * PHASE;
        floatx4 accz = {0,0,0,0}, accr = {0,0,0,0}, accrh = {0,0,0,0}, accxh = {0,0,0,0};

        // x-part from prefetched registers (off the critical chain)
#pragma unroll
        for (int kt = 0; kt < 3; ++kt) {
            bf16x8 a = cvt8(pf[kt * 2], pf[kt * 2 + 1]);
            int kb = kt * 32 + q * 8;
            accz  = __builtin_amdgcn_mfma_f32_16x16x32_bf16(a, ld8(bsz + kb), accz, 0, 0, 0);
            accr  = __builtin_amdgcn_mfma_f32_16x16x32_bf16(a, ld8(bsr + kb), accr, 0, 0, 0);
            accxh = __builtin_amdgcn_mfma_f32_16x16x32_bf16(a, ld8(bsh + kb), accxh, 0, 0, 0);
        }
        {
            ushort8 t8 = {0, 0, 0, 0, 0, 0, 0, 0};
            if (q == 0) {
                t8[0] = f2bf(pft.x); t8[1] = f2bf(pft.y);
                t8[2] = f2bf(pft.z); t8[3] = f2bf(pft.w);
            }
            bf16x8 a = __builtin_bit_cast(bf16x8, t8);
            int kb = 96 + q * 8;
            accz  = __builtin_amdgcn_mfma_f32_16x16x32_bf16(a, ld8(bsz + kb), accz, 0, 0, 0);
            accr  = __builtin_amdgcn_mfma_f32_16x16x32_bf16(a, ld8(bsr + kb), accr, 0, 0, 0);
            accxh = __builtin_amdgcn_mfma_f32_16x16x32_bf16(a, ld8(bsh + kb), accxh, 0, 0, 0);
        }

        // wait (per-wave, lane-parallel over the 44 relevant producer waves).
        // Poll enters with ZERO outstanding vmem (x-prefetch moved below).
        if (lane < 44) {
            if (fast) {
                int spin = 0;
                while (__hip_atomic_load(pollp, __ATOMIC_RELAXED, __HIP_MEMORY_SCOPE_AGENT) < t + 1) {
                    if (++spin > 64) __builtin_amdgcn_s_sleep(1);
                }
            } else {
                while (__hip_atomic_load(pollp, __ATOMIC_ACQUIRE, __HIP_MEMORY_SCOPE_AGENT) < t + 1)
                    __builtin_amdgcn_s_sleep(1);
            }
        }
        if (fast) l1_inv();   // fresh L1 for this wave's h reads

        // prefetch x for t+1 (issued here so its L3/HBM latency hides under
        // the A-ring + MFMA region instead of the poll's first vmcnt(0))
        {
            int tn = (t < 255) ? t + 1 : 255;
            int tok = enc[rowa * 256 + tn];
            const float* ep = emb + tok * 100;
#pragma unroll
            for (int kt = 0; kt < 3; ++kt) {
                pf[kt * 2]     = *(const floatx4*)(ep + kt * 32 + q * 8);
                pf[kt * 2 + 1] = *(const floatx4*)(ep + kt * 32 + q * 8 + 4);
            }
            pft = *(const floatx4*)(ep + 96);
        }

        // h-part: 22 K-tiles; ring-buffer prefetch depth 8 of hi/lo A-frags
        const ushort_t* arow = Asrc + rowa * AH_ROW + q * 8;
        bf16x8 ra[8], rb[8];
#pragma unroll
        for (int p = 0; p < 8; ++p) {
            ra[p] = ld8(arow + p * 32);
            rb[p] = ld8(arow + HP + p * 32);
        }
#pragma unroll
        for (int kt = 0; kt < 22; ++kt) {
            bf16x8 ahi = ra[kt & 7];
            bf16x8 alo = rb[kt & 7];
            if (kt + 8 < 22) {
                ra[kt & 7] = ld8(arow + (kt + 8) * 32);
                rb[kt & 7] = ld8(arow + HP + (kt + 8) * 32);
            }
            int kb = 128 + kt * 32 + q * 8;
            bf16x8 bz8 = ld8(bsz + kb), br8 = ld8(bsr + kb), bh8 = ld8(bsh + kb);
            accz  = __builtin_amdgcn_mfma_f32_16x16x32_bf16(ahi, bz8, accz, 0, 0, 0);
            accr  = __builtin_amdgcn_mfma_f32_16x16x32_bf16(ahi, br8, accr, 0, 0, 0);
            accrh = __builtin_amdgcn_mfma_f32_16x16x32_bf16(ahi, bh8, accrh, 0, 0, 0);
            accz  = __builtin_amdgcn_mfma_f32_16x16x32_bf16(alo, bz8, accz, 0, 0, 0);
            accr  = __builtin_amdgcn_mfma_f32_16x16x32_bf16(alo, br8, accr, 0, 0, 0);
            accrh = __builtin_amdgcn_mfma_f32_16x16x32_bf16(alo, bh8, accrh, 0, 0, 0);
        }

        // epilogue: fast gates, update h, publish hi/lo
#pragma unroll
        for (int i = 0; i < 4; i++) {
            int rowc = g * 32 + rt * 16 + q * 4 + i;
            float z = fast_rcp(1.f + fast_exp(-(accz[i] + bzc)));
            float r = fast_rcp(1.f + fast_exp(-(accr[i] + brc)));
            float e2 = fast_exp(2.f * (accxh[i] + b0h + r * (accrh[i] + b1h)));
            float hh = 1.f - 2.f * fast_rcp(e2 + 1.f);
            float h = z * hown[i] + (1.f - z) * hh;
            if (j >= 700) h = 0.f;
            hown[i] = h;
            ushort_t hi = f2bf(h);
            Adst[rowc * AH_ROW + j] = hi;
            Adst[rowc * AH_ROW + HP + j] = f2bf(h - bf2f(hi));
        }

        // per-wave publish: drain own stores, then flag
        if (fast) {
            wave_drain();
            if (lane == 0)
                __hip_atomic_store(myflag, t + 2, __ATOMIC_RELAXED, __HIP_MEMORY_SCOPE_AGENT);
        } else {
            if (lane == 0)
                __hip_atomic_store(myflag, t + 2, __ATOMIC_RELEASE, __HIP_MEMORY_SCOPE_AGENT);
            else
                __threadfence();
        }

        // ---- R18 probe: 4 chained agent-atomic RTs on lane0 of every wave.
        // Address-dependent (flag values < 2^20 so offset is always 0) =>
        // strictly serialized; period += 4 x RT_agent. Decode from dur.
        if (fast && lane == 0) {
            int pv = 0;
#pragma unroll
            for (int u = 0; u < 4; ++u) {
                pv = __hip_atomic_load(probep + (pv >> 20), __ATOMIC_RELAXED,
                                       __HIP_MEMORY_SCOPE_AGENT);
            }
            asm volatile("" :: "v"(pv));
        }
    }

    // ---- final output -------------------------------------------------------
#pragma unroll
    for (int i = 0; i < 4; i++) {
        int rowc = g * 32 + rt * 16 + q * 4 + i;
        if (j >= 200 && j < 700)
            out[rowc * 500 + (j - 200)] = hown[i];
    }
}

extern "C" void kernel_launch(void* const* d_in, const int* in_sizes, int n_in,
                              void* d_out, int out_size, void* d_ws, size_t ws_size,
                              hipStream_t stream) {
    (void)in_sizes; (void)n_in; (void)out_size; (void)ws_size;
    const int*   enc  = (const int*)d_in[0];
    const float* lab  = (const float*)d_in[1];
    const float* emb  = (const float*)d_in[2];
    const float* W1   = (const float*)d_in[3];
    const float* b1   = (const float*)d_in[4];
    const float* Wx   = (const float*)d_in[5];
    float*       Wh   = (float*)d_in[6];
    const float* bias = (const float*)d_in[7];

    int*   cnt = (int*)d_ws;               // 5.2 KB of scratch used
    float* out = (float*)d_out;

    init_cnt<<<1, 1024, 0, stream>>>(cnt);

    hipFuncSetAttribute((const void*)gru_main,
                        hipFuncAttributeMaxDynamicSharedMemorySize, 96 * SB * 2);
    gru_main<<<NBLK, 256, 96 * SB * 2, stream>>>(enc, emb, Wx, Wh, lab, W1, b1,
                                                 bias, out, cnt);
}